// Round 1
// baseline (408.070 us; speedup 1.0000x reference)
//
#include <hip/hip_runtime.h>
#include <hip/hip_bf16.h>
#include <stdint.h>

typedef short bf16x8 __attribute__((ext_vector_type(8)));
typedef float f32x4 __attribute__((ext_vector_type(4)));

#define NB 4
#define NL 2048
#define ND 1024
#define NH 16
#define NDK 64
#define NM (NB*NL)

__device__ __forceinline__ ushort f2bf(float f) {
  __bf16 h = (__bf16)f;
  return __builtin_bit_cast(unsigned short, h);
}

// async global->LDS, 16B per lane. lds base must be wave-uniform; HW adds lane*16.
__device__ __forceinline__ void gload16(const void* g, void* l) {
  __builtin_amdgcn_global_load_lds(
      (__attribute__((address_space(1))) void*)(uintptr_t)g,
      (__attribute__((address_space(3))) void*)(uint32_t)(uintptr_t)l,
      16, 0, 0);
}

// ---------------- fp32 -> bf16 conversion of x, Wq, Wk, Wv, Wo ----------------
__global__ void convert_all(const float* __restrict__ x, const float* __restrict__ wq,
                            const float* __restrict__ wk, const float* __restrict__ wv,
                            const float* __restrict__ wo, ushort* __restrict__ o) {
  long i = (long)blockIdx.x * 256 + threadIdx.x;   // float4 index
  const long NX = 2097152;   // x float4s (8.4M/4)
  const long NW = 262144;    // per-W float4s (1M/4)
  const float4* s;
  long off;
  if (i < NX) { s = (const float4*)x; off = i; }
  else {
    long j = i - NX;
    int wsel = (int)(j >> 18);
    off = j & (NW - 1);
    s = (const float4*)(wsel == 0 ? wq : wsel == 1 ? wk : wsel == 2 ? wv : wo);
  }
  float4 v = s[off];
  ushort4 r;
  r.x = f2bf(v.x); r.y = f2bf(v.y); r.z = f2bf(v.z); r.w = f2bf(v.w);
  ((ushort4*)o)[i] = r;
}

// ---------------- GEMM: C[m,n] = sum_k A[m,k] * B[n,k]  (B^T layout) ----------------
// MODE 0: A=x_bf16 [8192,1024]; B in {Wq,Wk,Wv} selected by n-tile; out bf16 [B,H,L,DK]
// MODE 1: A=attnout [8192,1024]; B=Wo; out fp32 [8192,1024]
template<int MODE>
__global__ __launch_bounds__(256, 2)
void gemm_bt(const ushort* __restrict__ A,
             const ushort* __restrict__ Bq, const ushort* __restrict__ Bk, const ushort* __restrict__ Bv,
             ushort* __restrict__ Oq, ushort* __restrict__ Ok, ushort* __restrict__ Ov,
             float* __restrict__ OF) {
  __shared__ __align__(16) ushort lA[128 * 32];
  __shared__ __align__(16) ushort lB[128 * 32];
  const int t = threadIdx.x;
  const int w = t >> 6, l = t & 63;
  const int lr = l & 15, lh = l >> 4;
  const int m0 = blockIdx.x * 128;
  const int ng = blockIdx.y * 128;
  const ushort* Bp;
  ushort* Op = nullptr;
  int n0;
  if (MODE == 0) {
    int mi = ng >> 10;
    Bp = (mi == 0) ? Bq : (mi == 1) ? Bk : Bv;
    Op = (mi == 0) ? Oq : (mi == 1) ? Ok : Ov;
    n0 = ng & 1023;
  } else {
    Bp = Bq;
    n0 = ng;
  }
  const int wrow = (w >> 1) * 64, wcol = (w & 1) * 64;
  const int r = t >> 2, c = t & 3;  // staging: 64 rows x 4 chunks(16B) per 256-thread issue
  const ushort* gA0 = A + (size_t)(m0 + r) * ND + c * 8;
  const ushort* gA1 = A + (size_t)(m0 + 64 + r) * ND + c * 8;
  const ushort* gB0 = Bp + (size_t)(n0 + r) * ND + c * 8;
  const ushort* gB1 = Bp + (size_t)(n0 + 64 + r) * ND + c * 8;
  ushort* lA0 = lA + (w * 64) * 8;          // wave-uniform LDS bases
  ushort* lA1 = lA + (256 + w * 64) * 8;
  ushort* lB0 = lB + (w * 64) * 8;
  ushort* lB1 = lB + (256 + w * 64) * 8;

  f32x4 acc[4][4] = {};
  for (int kt = 0; kt < ND; kt += 32) {
    __syncthreads();
    gload16(gA0 + kt, lA0);
    gload16(gA1 + kt, lA1);
    gload16(gB0 + kt, lB0);
    gload16(gB1 + kt, lB1);
    __syncthreads();
    bf16x8 af[4], bfr[4];
#pragma unroll
    for (int mt = 0; mt < 4; mt++)
      af[mt] = *(const bf16x8*)&lA[(wrow + mt * 16 + lr) * 32 + lh * 8];
#pragma unroll
    for (int nt = 0; nt < 4; nt++)
      bfr[nt] = *(const bf16x8*)&lB[(wcol + nt * 16 + lr) * 32 + lh * 8];
#pragma unroll
    for (int mt = 0; mt < 4; mt++)
#pragma unroll
      for (int nt = 0; nt < 4; nt++)
        acc[mt][nt] = __builtin_amdgcn_mfma_f32_16x16x32_bf16(af[mt], bfr[nt], acc[mt][nt], 0, 0, 0);
  }
  // epilogue: C/D layout col = lane&15, row = (lane>>4)*4 + reg
#pragma unroll
  for (int mt = 0; mt < 4; mt++) {
#pragma unroll
    for (int nt = 0; nt < 4; nt++) {
#pragma unroll
      for (int j = 0; j < 4; j++) {
        int m = m0 + wrow + mt * 16 + lh * 4 + j;
        int n = wcol + nt * 16 + lr;
        if (MODE == 0) {
          int nl = n0 + n;
          int b = m >> 11, ll = m & 2047;
          int h = nl >> 6, dk = nl & 63;
          Op[(((size_t)(b * NH + h)) * NL + ll) * NDK + dk] = f2bf(acc[mt][nt][j]);
        } else {
          OF[(size_t)m * ND + ng + n] = acc[mt][nt][j];
        }
      }
    }
  }
}

// ---------------- causal flash attention ----------------
// grid: (L/64, B*H). 4 waves/block; wave w owns q rows [qb*64+w*16, +16), full DK=64.
__global__ __launch_bounds__(256, 2)
void attn_fwd(const ushort* __restrict__ Q, const ushort* __restrict__ Kg,
              const ushort* __restrict__ Vg, ushort* __restrict__ O) {
  __shared__ __align__(16) ushort lK[64 * 72];       // K tile [k][d], +8 pad
  __shared__ __align__(16) ushort lV[64 * 72];       // V^T tile [d][k], +8 pad
  __shared__ __align__(16) ushort lP[4][16 * 72];    // per-wave P tile [q][k]
  const int t = threadIdx.x;
  const int w = t >> 6, l = t & 63;
  const int lr = l & 15, lh = l >> 4;
  const int qb = blockIdx.x;
  const int bh = blockIdx.y;
  const size_t base = (size_t)bh * NL * NDK;
  const int q0w = qb * 64 + w * 16;

  bf16x8 qf[2];
  {
    const ushort* qp = Q + base + (size_t)(q0w + lr) * NDK + lh * 8;
    qf[0] = *(const bf16x8*)qp;
    qf[1] = *(const bf16x8*)(qp + 32);
  }
  float m_run[4], l_run[4];
  f32x4 accO[4] = {};
#pragma unroll
  for (int j = 0; j < 4; j++) { m_run[j] = -1e30f; l_run[j] = 0.f; }

  const int nkv = qb + 1;
  for (int kv = 0; kv < nkv; ++kv) {
    const int kv0 = kv * 64;
    __syncthreads();
    // stage K (row-major, padded) and V (transposed, padded)
#pragma unroll
    for (int i = 0; i < 2; i++) {
      int e = t + i * 256;
      int rr = e >> 3, cc = e & 7;
      int4 kd = *(const int4*)(Kg + base + (size_t)(kv0 + rr) * NDK + cc * 8);
      *(int4*)&lK[rr * 72 + cc * 8] = kd;
      int4 vd = *(const int4*)(Vg + base + (size_t)(kv0 + rr) * NDK + cc * 8);
      const ushort* vs = (const ushort*)&vd;
#pragma unroll
      for (int j = 0; j < 8; j++) lV[(cc * 8 + j) * 72 + rr] = vs[j];
    }
    __syncthreads();
    // S = Q K^T (per 16-col k-tile), fp32
    f32x4 s[4];
#pragma unroll
    for (int kt = 0; kt < 4; kt++) {
      bf16x8 kf0 = *(const bf16x8*)&lK[(kt * 16 + lr) * 72 + lh * 8];
      bf16x8 kf1 = *(const bf16x8*)&lK[(kt * 16 + lr) * 72 + 32 + lh * 8];
      f32x4 z = {};
      z = __builtin_amdgcn_mfma_f32_16x16x32_bf16(qf[0], kf0, z, 0, 0, 0);
      s[kt] = __builtin_amdgcn_mfma_f32_16x16x32_bf16(qf[1], kf1, z, 0, 0, 0);
    }
    // scale + causal mask (only diagonal kv block needs masking)
    if (kv == qb) {
#pragma unroll
      for (int kt = 0; kt < 4; kt++) {
        int kgl = kv0 + kt * 16 + lr;
#pragma unroll
        for (int j = 0; j < 4; j++) {
          int qgl = q0w + lh * 4 + j;
          float sv = s[kt][j] * 0.125f;
          s[kt][j] = (kgl <= qgl) ? sv : -1e30f;
        }
      }
    } else {
#pragma unroll
      for (int kt = 0; kt < 4; kt++)
#pragma unroll
        for (int j = 0; j < 4; j++) s[kt][j] *= 0.125f;
    }
    // online softmax (rows live in 16-lane groups; reduce with shfl_xor 1/2/4/8)
    float f_[4];
#pragma unroll
    for (int j = 0; j < 4; j++) {
      float mx = fmaxf(fmaxf(s[0][j], s[1][j]), fmaxf(s[2][j], s[3][j]));
      mx = fmaxf(mx, __shfl_xor(mx, 1));
      mx = fmaxf(mx, __shfl_xor(mx, 2));
      mx = fmaxf(mx, __shfl_xor(mx, 4));
      mx = fmaxf(mx, __shfl_xor(mx, 8));
      float mnew = fmaxf(m_run[j], mx);
      f_[j] = __expf(m_run[j] - mnew);
      m_run[j] = mnew;
      float sum = 0.f;
#pragma unroll
      for (int kt = 0; kt < 4; kt++) {
        float p = __expf(s[kt][j] - mnew);
        s[kt][j] = p;
        sum += p;
      }
      sum += __shfl_xor(sum, 1);
      sum += __shfl_xor(sum, 2);
      sum += __shfl_xor(sum, 4);
      sum += __shfl_xor(sum, 8);
      l_run[j] = l_run[j] * f_[j] + sum;
    }
#pragma unroll
    for (int nt = 0; nt < 4; nt++)
#pragma unroll
      for (int j = 0; j < 4; j++) accO[nt][j] *= f_[j];
    // P -> LDS (bf16) to re-fragment as PV A-operand
#pragma unroll
    for (int kt = 0; kt < 4; kt++)
#pragma unroll
      for (int j = 0; j < 4; j++)
        lP[w][(lh * 4 + j) * 72 + kt * 16 + lr] = f2bf(s[kt][j]);
    asm volatile("s_waitcnt lgkmcnt(0)" ::: "memory");
    bf16x8 pa0 = *(const bf16x8*)&lP[w][lr * 72 + lh * 8];
    bf16x8 pa1 = *(const bf16x8*)&lP[w][lr * 72 + 32 + lh * 8];
#pragma unroll
    for (int nt = 0; nt < 4; nt++) {
      bf16x8 vf0 = *(const bf16x8*)&lV[(nt * 16 + lr) * 72 + lh * 8];
      bf16x8 vf1 = *(const bf16x8*)&lV[(nt * 16 + lr) * 72 + 32 + lh * 8];
      accO[nt] = __builtin_amdgcn_mfma_f32_16x16x32_bf16(pa0, vf0, accO[nt], 0, 0, 0);
      accO[nt] = __builtin_amdgcn_mfma_f32_16x16x32_bf16(pa1, vf1, accO[nt], 0, 0, 0);
    }
  }
  // write O (attn out) to [B, L, D] bf16
  const int b = bh >> 4, h = bh & 15;
#pragma unroll
  for (int j = 0; j < 4; j++) {
    float inv = 1.0f / l_run[j];
    int qg = q0w + lh * 4 + j;
    size_t rowbase = ((size_t)b * NL + qg) * ND + h * NDK;
#pragma unroll
    for (int nt = 0; nt < 4; nt++)
      O[rowbase + nt * 16 + lr] = f2bf(accO[nt][j] * inv);
  }
}

extern "C" void kernel_launch(void* const* d_in, const int* in_sizes, int n_in,
                              void* d_out, int out_size, void* d_ws, size_t ws_size,
                              hipStream_t stream) {
  const float* x = (const float*)d_in[0];
  const float* wq = (const float*)d_in[1];
  const float* wk = (const float*)d_in[2];
  const float* wv = (const float*)d_in[3];
  const float* wo = (const float*)d_in[4];
  char* ws = (char*)d_ws;
  // bf16 workspace layout (bytes)
  ushort* xb  = (ushort*)(ws);               // 16,777,216
  ushort* wqb = (ushort*)(ws + 16777216);    //  2,097,152
  ushort* wkb = (ushort*)(ws + 18874368);
  ushort* wvb = (ushort*)(ws + 20971520);
  ushort* wob = (ushort*)(ws + 23068672);
  ushort* Qb  = (ushort*)(ws + 25165824);    // [B,H,L,DK] bf16
  ushort* Kb  = (ushort*)(ws + 41943040);
  ushort* Vb  = (ushort*)(ws + 58720256);
  ushort* Ob  = (ushort*)(ws + 75497472);    // [B,L,D] bf16

  convert_all<<<12288, 256, 0, stream>>>(x, wq, wk, wv, wo, xb);
  gemm_bt<0><<<dim3(64, 24), 256, 0, stream>>>(xb, wqb, wkb, wvb, Qb, Kb, Vb, nullptr);
  attn_fwd<<<dim3(32, 64), 256, 0, stream>>>(Qb, Kb, Vb, Ob);
  gemm_bt<1><<<dim3(64, 8), 256, 0, stream>>>(Ob, wob, nullptr, nullptr,
                                              nullptr, nullptr, nullptr, (float*)d_out);
}

// Round 2
// 217.927 us; speedup vs baseline: 1.8725x; 1.8725x over previous
//
#include <hip/hip_runtime.h>
#include <hip/hip_bf16.h>
#include <stdint.h>

typedef short bf16x8 __attribute__((ext_vector_type(8)));
typedef float f32x4 __attribute__((ext_vector_type(4)));
typedef float f32x16 __attribute__((ext_vector_type(16)));
typedef unsigned int uint4v __attribute__((ext_vector_type(4)));

#define NB 4
#define NL 2048
#define ND 1024
#define NH 16
#define NDK 64
#define NM (NB*NL)

__device__ __forceinline__ ushort f2bf(float f) {
  __bf16 h = (__bf16)f;
  return __builtin_bit_cast(unsigned short, h);
}

__device__ __forceinline__ unsigned int cvtpk(float lo, float hi) {
  unsigned int d;
  asm("v_cvt_pk_bf16_f32 %0, %1, %2" : "=v"(d) : "v"(lo), "v"(hi));
  return d;
}

// async global->LDS, 16B per lane. lds base must be wave-uniform; HW adds lane*16.
__device__ __forceinline__ void gload16(const void* g, void* l) {
  __builtin_amdgcn_global_load_lds(
      (__attribute__((address_space(1))) void*)(uintptr_t)g,
      (__attribute__((address_space(3))) void*)(uint32_t)(uintptr_t)l,
      16, 0, 0);
}

__device__ __forceinline__ f32x16 mfma32(bf16x8 a, bf16x8 b, f32x16 c) {
  return __builtin_amdgcn_mfma_f32_32x32x16_bf16(a, b, c, 0, 0, 0);
}

// ---------------- fp32 -> bf16 conversion of x, Wq, Wk, Wv, Wo ----------------
__global__ void convert_all(const float* __restrict__ x, const float* __restrict__ wq,
                            const float* __restrict__ wk, const float* __restrict__ wv,
                            const float* __restrict__ wo, ushort* __restrict__ o) {
  long i = (long)blockIdx.x * 256 + threadIdx.x;   // float4 index
  const long NX = 2097152;   // x float4s
  const long NW = 262144;    // per-W float4s
  const float4* s;
  long off;
  if (i < NX) { s = (const float4*)x; off = i; }
  else {
    long j = i - NX;
    int wsel = (int)(j >> 18);
    off = j & (NW - 1);
    s = (const float4*)(wsel == 0 ? wq : wsel == 1 ? wk : wsel == 2 ? wv : wo);
  }
  float4 v = s[off];
  ushort4 r;
  r.x = f2bf(v.x); r.y = f2bf(v.y); r.z = f2bf(v.z); r.w = f2bf(v.w);
  ((ushort4*)o)[i] = r;
}

// ---------------- GEMM: C[m,n] = sum_k A[m,k] * B[n,k]  (B^T layout) ----------------
// MODE 0: A=x_bf16 [8192,1024]; B in {Wq,Wk,Wv}; out Q,K as [B,H,L,DK], V as [B,H,DK,L] (transposed)
// MODE 1: A=attnout [8192,1024]; B=Wo; out fp32 [8192,1024]
template<int MODE>
__global__ __launch_bounds__(256, 2)
void gemm_bt(const ushort* __restrict__ A,
             const ushort* __restrict__ Bq, const ushort* __restrict__ Bk, const ushort* __restrict__ Bv,
             ushort* __restrict__ Oq, ushort* __restrict__ Ok, ushort* __restrict__ Ov,
             float* __restrict__ OF) {
  __shared__ __align__(16) ushort lA[128 * 32];
  __shared__ __align__(16) ushort lB[128 * 32];
  const int t = threadIdx.x;
  const int w = t >> 6, l = t & 63;
  const int lr = l & 15, lh = l >> 4;
  const int m0 = blockIdx.x * 128;
  const int ng = blockIdx.y * 128;
  const ushort* Bp;
  ushort* Op = nullptr;
  int mi = 0, n0;
  if (MODE == 0) {
    mi = ng >> 10;
    Bp = (mi == 0) ? Bq : (mi == 1) ? Bk : Bv;
    Op = (mi == 0) ? Oq : (mi == 1) ? Ok : Ov;
    n0 = ng & 1023;
  } else {
    Bp = Bq;
    n0 = ng;
  }
  const int wrow = (w >> 1) * 64, wcol = (w & 1) * 64;
  const int r = t >> 2, c = t & 3;
  const ushort* gA0 = A + (size_t)(m0 + r) * ND + c * 8;
  const ushort* gA1 = A + (size_t)(m0 + 64 + r) * ND + c * 8;
  const ushort* gB0 = Bp + (size_t)(n0 + r) * ND + c * 8;
  const ushort* gB1 = Bp + (size_t)(n0 + 64 + r) * ND + c * 8;
  ushort* lA0 = lA + (w * 64) * 8;
  ushort* lA1 = lA + (256 + w * 64) * 8;
  ushort* lB0 = lB + (w * 64) * 8;
  ushort* lB1 = lB + (256 + w * 64) * 8;

  f32x4 acc[4][4] = {};
  for (int kt = 0; kt < ND; kt += 32) {
    __syncthreads();
    gload16(gA0 + kt, lA0);
    gload16(gA1 + kt, lA1);
    gload16(gB0 + kt, lB0);
    gload16(gB1 + kt, lB1);
    __syncthreads();
    bf16x8 af[4], bfr[4];
#pragma unroll
    for (int mt = 0; mt < 4; mt++)
      af[mt] = *(const bf16x8*)&lA[(wrow + mt * 16 + lr) * 32 + lh * 8];
#pragma unroll
    for (int nt = 0; nt < 4; nt++)
      bfr[nt] = *(const bf16x8*)&lB[(wcol + nt * 16 + lr) * 32 + lh * 8];
#pragma unroll
    for (int mt = 0; mt < 4; mt++)
#pragma unroll
      for (int nt = 0; nt < 4; nt++)
        acc[mt][nt] = __builtin_amdgcn_mfma_f32_16x16x32_bf16(af[mt], bfr[nt], acc[mt][nt], 0, 0, 0);
  }
  // epilogue: C/D layout col = lane&15, row = (lane>>4)*4 + reg
#pragma unroll
  for (int mt = 0; mt < 4; mt++) {
#pragma unroll
    for (int nt = 0; nt < 4; nt++) {
#pragma unroll
      for (int j = 0; j < 4; j++) {
        int m = m0 + wrow + mt * 16 + lh * 4 + j;
        int n = wcol + nt * 16 + lr;
        if (MODE == 0) {
          int nl = n0 + n;
          int b = m >> 11, ll = m & 2047;
          int h = nl >> 6, dk = nl & 63;
          if (mi == 2)  // V stored transposed: [B,H,DK,L]
            Op[(((size_t)(b * NH + h)) * NDK + dk) * NL + ll] = f2bf(acc[mt][nt][j]);
          else
            Op[(((size_t)(b * NH + h)) * NL + ll) * NDK + dk] = f2bf(acc[mt][nt][j]);
        } else {
          OF[(size_t)m * ND + ng + n] = acc[mt][nt][j];
        }
      }
    }
  }
}

// ---------------- causal flash attention, 8-wave 32x32 swapped-operand ----------------
// grid: (L/256, B*H), 512 threads. Wave w owns q rows [qb*256 + w*32, +32).
// S^T = mfma(K_frag, Q_frag): lane holds S[q = l&31][kv set] in 2x f32x16.
// O^T = mfma(VT_frag, PT_frag): lane holds O[q = l&31][dk set].
__global__ __launch_bounds__(512, 2)
void attn_fwd(const ushort* __restrict__ Q, const ushort* __restrict__ Kg,
              const ushort* __restrict__ VT, ushort* __restrict__ O) {
  __shared__ __align__(16) ushort lK[2][64 * 64];   // swizzled: slot(r,c) holds data(r, c^(r&7))
  __shared__ __align__(16) ushort lV[2][64 * 64];   // V^T rows (dk), same swizzle
  const int t = threadIdx.x;
  const int w = t >> 6, l = t & 63;
  const int l31 = l & 31, hi = l >> 5;
  const int qb = blockIdx.x, bh = blockIdx.y;
  const size_t base = (size_t)bh * (NL * NDK);
  const int q0w = qb * 256 + w * 32;
  const int ktmax = q0w >> 6;          // wave's diagonal tile
  const int NT = qb * 4 + 4;

  // Q fragments in registers: qf[sl] = Q[q0w + l31][sl*16 + hi*8 .. +8]
  bf16x8 qf[4];
  {
    const ushort* qp = Q + base + (size_t)(q0w + l31) * NDK + hi * 8;
#pragma unroll
    for (int sl = 0; sl < 4; sl++) qf[sl] = *(const bf16x8*)(qp + sl * 16);
  }

  // staging: thread t fills LDS slot t (16B). slot row sr, slot chunk sc;
  // source chunk = sc ^ (sr&7)  (pre-swizzled global address, linear LDS dest)
  const int sr = t >> 3, sc = t & 7;
  const int gc = sc ^ (sr & 7);
  const ushort* gK = Kg + base + (size_t)sr * NDK + gc * 8;
  const ushort* gV = VT + base + (size_t)sr * NL + gc * 8;
  ushort* ldK0 = &lK[0][w * 512];  // wave-uniform base; HW adds lane*16B
  ushort* ldK1 = &lK[1][w * 512];
  ushort* ldV0 = &lV[0][w * 512];
  ushort* ldV1 = &lV[1][w * 512];

  float m_run = -1e30f, l_run = 0.f;
  f32x16 accO0 = {}, accO1 = {};

  // prologue: stage tile 0 into buf 0
  gload16(gK, ldK0);
  gload16(gV, ldV0);

  for (int kt = 0; kt < NT; kt++) {
    const int buf = kt & 1;
    __syncthreads();   // drains vmcnt (stage kt complete) + closes previous compute
    if (kt + 1 < NT) {
      gload16(gK + (size_t)(kt + 1) * 64 * NDK, buf ? ldK0 : ldK1);
      gload16(gV + (kt + 1) * 64,               buf ? ldV0 : ldV1);
    }
    if (kt <= ktmax) {
      const int kv0 = kt * 64;
      const ushort* bK = lK[buf];
      const ushort* bV = lV[buf];
      const int swz = l31 & 7;
      // ---- QK^T:  S^T[kv][q],  kv halves in s0 (kv0..31), s1 (kv32..63) ----
      f32x16 s0 = {}, s1 = {};
#pragma unroll
      for (int sl = 0; sl < 4; sl++) {
        int c = 2 * sl + hi;
        bf16x8 kf0 = *(const bf16x8*)&bK[l31 * 64 + ((c ^ swz) * 8)];
        bf16x8 kf1 = *(const bf16x8*)&bK[(32 + l31) * 64 + ((c ^ swz) * 8)];
        s0 = mfma32(kf0, qf[sl], s0);
        s1 = mfma32(kf1, qf[sl], s1);
      }
      // scale
#pragma unroll
      for (int r = 0; r < 16; r++) { s0[r] *= 0.125f; s1[r] *= 0.125f; }
      // causal mask on the wave's diagonal tile
      if (kt == ktmax) {
        const int qrel = q0w + l31 - kv0;
#pragma unroll
        for (int r = 0; r < 16; r++) {
          int kvo = (r & 3) + 8 * (r >> 2) + 4 * hi;
          if (kvo > qrel) s0[r] = -1e30f;
          if (kvo + 32 > qrel) s1[r] = -1e30f;
        }
      }
      // ---- online softmax (q = l&31 is lane-local; combine hi halves via xor-32) ----
      float mx = s0[0];
#pragma unroll
      for (int r = 1; r < 16; r++) mx = fmaxf(mx, s0[r]);
#pragma unroll
      for (int r = 0; r < 16; r++) mx = fmaxf(mx, s1[r]);
      mx = fmaxf(mx, __shfl_xor(mx, 32));
      float fscale = 1.0f;
      if (!__all(mx <= m_run + 8.0f)) {
        float mn = fmaxf(m_run, mx);
        fscale = __expf(m_run - mn);
        m_run = mn;
#pragma unroll
        for (int r = 0; r < 16; r++) { accO0[r] *= fscale; accO1[r] *= fscale; }
      }
      float sum = 0.f;
#pragma unroll
      for (int r = 0; r < 16; r++) { s0[r] = __expf(s0[r] - m_run); sum += s0[r]; }
#pragma unroll
      for (int r = 0; r < 16; r++) { s1[r] = __expf(s1[r] - m_run); sum += s1[r]; }
      sum += __shfl_xor(sum, 32);
      l_run = l_run * fscale + sum;
      // ---- pack P^T fragments: pa[ks] = P[q=l&31][kv = ks*16 + hi*8 + j] ----
      bf16x8 pa[4];
#pragma unroll
      for (int ks = 0; ks < 4; ks++) {
        const int k2 = (ks & 1) * 8;
        unsigned int a0, a1, b0, b1;
        if (ks >> 1) {
          a0 = cvtpk(s1[k2 + 0], s1[k2 + 1]); a1 = cvtpk(s1[k2 + 2], s1[k2 + 3]);
          b0 = cvtpk(s1[k2 + 4], s1[k2 + 5]); b1 = cvtpk(s1[k2 + 6], s1[k2 + 7]);
        } else {
          a0 = cvtpk(s0[k2 + 0], s0[k2 + 1]); a1 = cvtpk(s0[k2 + 2], s0[k2 + 3]);
          b0 = cvtpk(s0[k2 + 4], s0[k2 + 5]); b1 = cvtpk(s0[k2 + 6], s0[k2 + 7]);
        }
        // half-swap: lanes hi=0 need (a_own, partner_a); hi=1 need (partner_b, b_own)
        unsigned int a0s = __shfl_xor(a0, 32), a1s = __shfl_xor(a1, 32);
        unsigned int b0s = __shfl_xor(b0, 32), b1s = __shfl_xor(b1, 32);
        uint4v pd;
        pd[0] = hi ? b0s : a0;   // j0,j1
        pd[1] = hi ? b1s : a1;   // j2,j3
        pd[2] = hi ? b0 : a0s;   // j4,j5
        pd[3] = hi ? b1 : a1s;   // j6,j7
        pa[ks] = __builtin_bit_cast(bf16x8, pd);
      }
      // ---- PV: O^T += V^T-frag x P^T-frag ----
#pragma unroll
      for (int ks = 0; ks < 4; ks++) {
        int c = 2 * ks + hi;
        bf16x8 vf0 = *(const bf16x8*)&bV[l31 * 64 + ((c ^ swz) * 8)];
        bf16x8 vf1 = *(const bf16x8*)&bV[(32 + l31) * 64 + ((c ^ swz) * 8)];
        accO0 = mfma32(vf0, pa[ks], accO0);
        accO1 = mfma32(vf1, pa[ks], accO1);
      }
    }
  }
  // ---- epilogue: lane l holds O[q = q0w + l31][dk = (r&3)+8*(r>>2)+4*hi (+32)] ----
  const int b = bh >> 4, h = bh & 15;
  const float inv = 1.0f / l_run;
  const int q = q0w + l31;
  ushort* orow = O + ((size_t)b * NL + q) * ND + h * NDK;
#pragma unroll
  for (int g = 0; g < 4; g++) {
    ushort4 o0, o1;
    o0.x = f2bf(accO0[4 * g + 0] * inv); o0.y = f2bf(accO0[4 * g + 1] * inv);
    o0.z = f2bf(accO0[4 * g + 2] * inv); o0.w = f2bf(accO0[4 * g + 3] * inv);
    o1.x = f2bf(accO1[4 * g + 0] * inv); o1.y = f2bf(accO1[4 * g + 1] * inv);
    o1.z = f2bf(accO1[4 * g + 2] * inv); o1.w = f2bf(accO1[4 * g + 3] * inv);
    *(ushort4*)&orow[8 * g + 4 * hi] = o0;
    *(ushort4*)&orow[32 + 8 * g + 4 * hi] = o1;
  }
}

extern "C" void kernel_launch(void* const* d_in, const int* in_sizes, int n_in,
                              void* d_out, int out_size, void* d_ws, size_t ws_size,
                              hipStream_t stream) {
  const float* x = (const float*)d_in[0];
  const float* wq = (const float*)d_in[1];
  const float* wk = (const float*)d_in[2];
  const float* wv = (const float*)d_in[3];
  const float* wo = (const float*)d_in[4];
  char* ws = (char*)d_ws;
  ushort* xb  = (ushort*)(ws);               // 16,777,216 B
  ushort* wqb = (ushort*)(ws + 16777216);
  ushort* wkb = (ushort*)(ws + 18874368);
  ushort* wvb = (ushort*)(ws + 20971520);
  ushort* wob = (ushort*)(ws + 23068672);
  ushort* Qb  = (ushort*)(ws + 25165824);    // [B,H,L,DK] bf16
  ushort* Kb  = (ushort*)(ws + 41943040);    // [B,H,L,DK]
  ushort* Vb  = (ushort*)(ws + 58720256);    // [B,H,DK,L] (transposed)
  ushort* Ob  = (ushort*)(ws + 75497472);    // [B,L,D] bf16

  convert_all<<<12288, 256, 0, stream>>>(x, wq, wk, wv, wo, xb);
  gemm_bt<0><<<dim3(64, 24), 256, 0, stream>>>(xb, wqb, wkb, wvb, Qb, Kb, Vb, nullptr);
  attn_fwd<<<dim3(8, 64), 512, 0, stream>>>(Qb, Kb, Vb, Ob);
  gemm_bt<1><<<dim3(64, 8), 256, 0, stream>>>(Ob, wob, nullptr, nullptr,
                                              nullptr, nullptr, nullptr, (float*)d_out);
}